// Round 1
// baseline (703.586 us; speedup 1.0000x reference)
//
#include <hip/hip_runtime.h>
#include <stdint.h>

#define T_SEQ 2048
#define DMODEL 4096
#define DKV 1024
#define DHEAD 128
#define NHEADS 32
#define NKV 8

typedef unsigned short u16;
typedef __attribute__((ext_vector_type(8))) __bf16 bf16x8;
typedef __attribute__((ext_vector_type(4))) float f32x4;

__device__ __forceinline__ u16 f2bf(float f) {
    uint32_t u = __builtin_bit_cast(uint32_t, f);
    u += 0x7FFFu + ((u >> 16) & 1u);
    return (u16)(u >> 16);
}
__device__ __forceinline__ float bf2f(u16 b) {
    return __builtin_bit_cast(float, (uint32_t)b << 16);
}

// ---------------- f32 -> bf16 convert (vectorized) ----------------
__global__ void cvt_kernel(const float* __restrict__ in, u16* __restrict__ out, int n4) {
    int i = blockIdx.x * blockDim.x + threadIdx.x;
    int stride = gridDim.x * blockDim.x;
    for (; i < n4; i += stride) {
        float4 v = ((const float4*)in)[i];
        ushort4 o;
        o.x = f2bf(v.x); o.y = f2bf(v.y); o.z = f2bf(v.z); o.w = f2bf(v.w);
        ((ushort4*)out)[i] = o;
    }
}

// ---------------- f32 [R][C] -> bf16 [C][R] transpose-convert ----------------
__global__ void tcvt_kernel(const float* __restrict__ in, u16* __restrict__ out, int R, int C) {
    __shared__ float tile[32][33];
    int c0 = blockIdx.x * 32, r0 = blockIdx.y * 32;
    int tx = threadIdx.x, ty = threadIdx.y;  // 32 x 8
#pragma unroll
    for (int i = 0; i < 32; i += 8)
        tile[ty + i][tx] = in[(size_t)(r0 + ty + i) * C + c0 + tx];
    __syncthreads();
#pragma unroll
    for (int i = 0; i < 32; i += 8)
        out[(size_t)(c0 + ty + i) * R + r0 + tx] = f2bf(tile[tx][ty + i]);
}

// ---------------- llama3 RoPE cos/sin tables [T][64] ----------------
__global__ void rope_setup(float* __restrict__ cosT, float* __restrict__ sinT) {
    int t = blockIdx.x, d = threadIdx.x;  // 64 threads
    const float TWO_PI = 6.283185307179586f;
    float fidx = (float)d * (1.0f / 64.0f);
    float freq = (1.0f / TWO_PI) * powf(500000.0f, -fidx);
    const float factor = 32.0f, lo = 1.0f, hi = 4.0f, L0 = 8192.0f;
    float fl = lo / L0, fh = hi / L0;
    float smooth = fminf(fmaxf((L0 * freq - lo) / (hi - lo), 0.0f), 1.0f);
    float fs = (1.0f - smooth) * (freq / factor) + smooth * freq;
    float fr = (freq < fl) ? (freq / factor) : freq;
    if (freq >= fl && freq <= fh) fr = fs;
    float ang = TWO_PI * (float)t * fr;
    cosT[t * 64 + d] = cosf(ang);
    sinT[t * 64 + d] = sinf(ang);
}

// ---------------- in-place RoPE on bf16 [T][nheads*128] ----------------
__global__ void rope_apply(u16* __restrict__ x, const float* __restrict__ cosT,
                           const float* __restrict__ sinT, int nheads) {
    int i = blockIdx.x * blockDim.x + threadIdx.x;
    int total = T_SEQ * nheads * 64;
    if (i >= total) return;
    int d = i & 63;
    int h = (i >> 6) % nheads;
    int t = i / (nheads * 64);
    size_t base = (size_t)t * (nheads * 128) + h * 128 + d;
    float x0 = bf2f(x[base]), x1 = bf2f(x[base + 64]);
    float c = cosT[t * 64 + d], s = sinT[t * 64 + d];
    x[base] = f2bf(x0 * c - x1 * s);
    x[base + 64] = f2bf(x1 * c + x0 * s);
}

// ---------------- GEMM: C[M,N] = A[M,K] * Bt[N,K]^T (bf16 in, f32 acc) ----------------
__launch_bounds__(256, 2)
__global__ void gemm_bt(const u16* __restrict__ A, const u16* __restrict__ Bt,
                        void* __restrict__ Cout, int M, int N, int K, int f32out) {
    __shared__ u16 As[128][72];
    __shared__ u16 Bs[128][72];
    int m0 = blockIdx.y * 128, n0 = blockIdx.x * 128;
    int tid = threadIdx.x;
    int wave = tid >> 6, lane = tid & 63;
    int l15 = lane & 15, lg = lane >> 4;
    int wm = (wave >> 1) * 64, wn = (wave & 1) * 64;
    f32x4 acc[4][4] = {};
    int rowb = tid >> 3, ch = (tid & 7) * 8;
    const u16* Ag = A + (size_t)(m0 + rowb) * K + ch;
    const u16* Bg = Bt + (size_t)(n0 + rowb) * K + ch;

    for (int k0 = 0; k0 < K; k0 += 64) {
        __syncthreads();
#pragma unroll
        for (int p = 0; p < 4; ++p) {
            *(uint4*)&As[rowb + p * 32][ch] = *(const uint4*)(Ag + (size_t)(p * 32) * K + k0);
            *(uint4*)&Bs[rowb + p * 32][ch] = *(const uint4*)(Bg + (size_t)(p * 32) * K + k0);
        }
        __syncthreads();
#pragma unroll
        for (int kk = 0; kk < 64; kk += 32) {
            bf16x8 af[4], bfr[4];
#pragma unroll
            for (int mi = 0; mi < 4; ++mi)
                af[mi] = *(const bf16x8*)&As[wm + mi * 16 + l15][kk + lg * 8];
#pragma unroll
            for (int ni = 0; ni < 4; ++ni)
                bfr[ni] = *(const bf16x8*)&Bs[wn + ni * 16 + l15][kk + lg * 8];
#pragma unroll
            for (int mi = 0; mi < 4; ++mi)
#pragma unroll
                for (int ni = 0; ni < 4; ++ni)
                    acc[mi][ni] = __builtin_amdgcn_mfma_f32_16x16x32_bf16(af[mi], bfr[ni], acc[mi][ni], 0, 0, 0);
        }
    }
#pragma unroll
    for (int mi = 0; mi < 4; ++mi)
#pragma unroll
        for (int ni = 0; ni < 4; ++ni)
#pragma unroll
            for (int r = 0; r < 4; ++r) {
                int row = m0 + wm + mi * 16 + lg * 4 + r;
                int col = n0 + wn + ni * 16 + l15;
                float v = acc[mi][ni][r];
                if (f32out)
                    ((float*)Cout)[(size_t)row * N + col] = v;
                else
                    ((u16*)Cout)[(size_t)row * N + col] = f2bf(v);
            }
}

// ---------------- flash attention (causal, GQA) ----------------
// grid: (T/64, NHEADS); block 256 = 4 waves x 16 q-rows
__launch_bounds__(256, 2)
__global__ void attn_kernel(const u16* __restrict__ Q, const u16* __restrict__ K,
                            const u16* __restrict__ V, u16* __restrict__ ctx) {
    __shared__ u16 Ks[64][136];
    __shared__ u16 Vs[128][72];   // transposed: [d][kv]
    __shared__ u16 Ps[4][16][72];
    int q0 = blockIdx.x * 64;
    int h = blockIdx.y;
    int kvh = h >> 2;
    int tid = threadIdx.x;
    int wave = tid >> 6, lane = tid & 63;
    int l15 = lane & 15, lg = lane >> 4;
    int qrow_base = q0 + wave * 16;

    bf16x8 qf[4];
#pragma unroll
    for (int kk = 0; kk < 4; ++kk)
        qf[kk] = *(const bf16x8*)&Q[(size_t)(qrow_base + l15) * DMODEL + h * DHEAD + kk * 32 + lg * 8];

    f32x4 acc_o[8] = {};
    float m_run[4], l_run[4];
#pragma unroll
    for (int r = 0; r < 4; ++r) { m_run[r] = -1e30f; l_run[r] = 0.0f; }

    int rowb = tid >> 4, cb = tid & 15, chb = cb * 8;
    int ntiles = (q0 >> 6) + 1;
    for (int tkv = 0; tkv < ntiles; ++tkv) {
        int kv0 = tkv * 64;
        __syncthreads();
#pragma unroll
        for (int p = 0; p < 4; ++p) {
            int r = rowb + p * 16;
            uint4 kvv = *(const uint4*)&K[(size_t)(kv0 + r) * DKV + kvh * DHEAD + chb];
            *(uint4*)&Ks[r][chb] = kvv;
            uint4 vvv = *(const uint4*)&V[(size_t)(kv0 + r) * DKV + kvh * DHEAD + chb];
            u16* vsp = (u16*)&vvv;
#pragma unroll
            for (int ii = 0; ii < 8; ++ii) {
                int j = (ii + cb) & 7;  // stagger to avoid 16-way bank conflict
                Vs[chb + j][r] = vsp[j];
            }
        }
        __syncthreads();

        // S = Q K^T   (16 x 64 per wave)
        f32x4 sacc[4] = {};
#pragma unroll
        for (int nt = 0; nt < 4; ++nt)
#pragma unroll
            for (int kk = 0; kk < 4; ++kk) {
                bf16x8 kf = *(const bf16x8*)&Ks[nt * 16 + l15][kk * 32 + lg * 8];
                sacc[nt] = __builtin_amdgcn_mfma_f32_16x16x32_bf16(qf[kk], kf, sacc[nt], 0, 0, 0);
            }

        const float scale = 0.08838834764831845f;  // 1/sqrt(128)
#pragma unroll
        for (int r = 0; r < 4; ++r) {
            int qrow = qrow_base + lg * 4 + r;
            float mx = m_run[r];
            float sv[4];
#pragma unroll
            for (int nt = 0; nt < 4; ++nt) {
                int kcol = kv0 + nt * 16 + l15;
                float s = sacc[nt][r] * scale;
                if (kcol > qrow) s = -1e30f;
                sv[nt] = s;
                mx = fmaxf(mx, s);
            }
#pragma unroll
            for (int m = 1; m < 16; m <<= 1) mx = fmaxf(mx, __shfl_xor(mx, m, 64));
            float alpha = __expf(m_run[r] - mx);
            m_run[r] = mx;
            float psum = 0.0f;
#pragma unroll
            for (int nt = 0; nt < 4; ++nt) {
                float p = __expf(sv[nt] - mx);
                psum += p;
                Ps[wave][lg * 4 + r][nt * 16 + l15] = f2bf(p);
            }
#pragma unroll
            for (int m = 1; m < 16; m <<= 1) psum += __shfl_xor(psum, m, 64);
            l_run[r] = l_run[r] * alpha + psum;
#pragma unroll
            for (int dt = 0; dt < 8; ++dt) acc_o[dt][r] *= alpha;
        }

        // PV: O += P (16x64) * V (64x128)
        bf16x8 pf[2];
#pragma unroll
        for (int kt = 0; kt < 2; ++kt)
            pf[kt] = *(const bf16x8*)&Ps[wave][l15][kt * 32 + lg * 8];
#pragma unroll
        for (int dt = 0; dt < 8; ++dt)
#pragma unroll
            for (int kt = 0; kt < 2; ++kt) {
                bf16x8 vf = *(const bf16x8*)&Vs[dt * 16 + l15][kt * 32 + lg * 8];
                acc_o[dt] = __builtin_amdgcn_mfma_f32_16x16x32_bf16(pf[kt], vf, acc_o[dt], 0, 0, 0);
            }
        __syncthreads();
    }

#pragma unroll
    for (int dt = 0; dt < 8; ++dt)
#pragma unroll
        for (int r = 0; r < 4; ++r) {
            int row = qrow_base + lg * 4 + r;
            int col = h * DHEAD + dt * 16 + l15;
            ctx[(size_t)row * DMODEL + col] = f2bf(acc_o[dt][r] / l_run[r]);
        }
}

extern "C" void kernel_launch(void* const* d_in, const int* in_sizes, int n_in,
                              void* d_out, int out_size, void* d_ws, size_t ws_size,
                              hipStream_t stream) {
    const float* resid = (const float*)d_in[0];
    const float* Wq = (const float*)d_in[1];
    const float* Wk = (const float*)d_in[2];
    const float* Wv = (const float*)d_in[3];
    const float* Wo = (const float*)d_in[4];

    char* ws = (char*)d_ws;
    u16* Xb   = (u16*)(ws + 0);           // 2048x4096 bf16 = 16 MiB
    u16* WqT  = (u16*)(ws + 16777216);    // 4096x4096 bf16 = 32 MiB
    u16* WkT  = (u16*)(ws + 50331648);    // 1024x4096 bf16 = 8 MiB
    u16* WvT  = (u16*)(ws + 58720256);    // 8 MiB
    u16* WoT  = (u16*)(ws + 67108864);    // 32 MiB
    u16* Qf   = (u16*)(ws + 100663296);   // 2048x4096 bf16
    u16* Kf   = (u16*)(ws + 117440512);   // 2048x1024 bf16
    u16* Vf   = (u16*)(ws + 121634816);   // 2048x1024 bf16
    u16* ctx  = (u16*)(ws + 125829120);   // 2048x4096 bf16
    float* cosT = (float*)(ws + 142606336);
    float* sinT = (float*)(ws + 143130624);

    // converts + transposes
    cvt_kernel<<<2048, 256, 0, stream>>>(resid, Xb, T_SEQ * DMODEL / 4);
    dim3 tb(32, 8);
    tcvt_kernel<<<dim3(DMODEL / 32, DMODEL / 32), tb, 0, stream>>>(Wq, WqT, DMODEL, DMODEL);
    tcvt_kernel<<<dim3(DKV / 32, DMODEL / 32), tb, 0, stream>>>(Wk, WkT, DMODEL, DKV);
    tcvt_kernel<<<dim3(DKV / 32, DMODEL / 32), tb, 0, stream>>>(Wv, WvT, DMODEL, DKV);
    tcvt_kernel<<<dim3(DMODEL / 32, DMODEL / 32), tb, 0, stream>>>(Wo, WoT, DMODEL, DMODEL);
    rope_setup<<<T_SEQ, 64, 0, stream>>>(cosT, sinT);

    // projections
    gemm_bt<<<dim3(DMODEL / 128, T_SEQ / 128), 256, 0, stream>>>(Xb, WqT, Qf, T_SEQ, DMODEL, DMODEL, 0);
    gemm_bt<<<dim3(DKV / 128, T_SEQ / 128), 256, 0, stream>>>(Xb, WkT, Kf, T_SEQ, DKV, DMODEL, 0);
    gemm_bt<<<dim3(DKV / 128, T_SEQ / 128), 256, 0, stream>>>(Xb, WvT, Vf, T_SEQ, DKV, DMODEL, 0);

    // RoPE (in-place)
    rope_apply<<<(T_SEQ * NHEADS * 64 + 255) / 256, 256, 0, stream>>>(Qf, cosT, sinT, NHEADS);
    rope_apply<<<(T_SEQ * NKV * 64 + 255) / 256, 256, 0, stream>>>(Kf, cosT, sinT, NKV);

    // attention
    attn_kernel<<<dim3(T_SEQ / 64, NHEADS), 256, 0, stream>>>(Qf, Kf, Vf, ctx);

    // output projection (f32 out)
    gemm_bt<<<dim3(DMODEL / 128, T_SEQ / 128), 256, 0, stream>>>(ctx, WoT, d_out, T_SEQ, DMODEL, DMODEL, 1);
}

// Round 2
// 687.714 us; speedup vs baseline: 1.0231x; 1.0231x over previous
//
#include <hip/hip_runtime.h>
#include <stdint.h>

#define T_SEQ 2048
#define DMODEL 4096
#define DKV 1024
#define DHEAD 128
#define NHEADS 32
#define NKV 8

typedef unsigned short u16;
typedef __attribute__((ext_vector_type(8))) __bf16 bf16x8;
typedef __attribute__((ext_vector_type(4))) float f32x4;

__device__ __forceinline__ u16 f2bf(float f) {
    uint32_t u = __builtin_bit_cast(uint32_t, f);
    u += 0x7FFFu + ((u >> 16) & 1u);
    return (u16)(u >> 16);
}
__device__ __forceinline__ float bf2f(u16 b) {
    return __builtin_bit_cast(float, (uint32_t)b << 16);
}

__device__ __forceinline__ void gload_lds16(const u16* g, u16* l) {
    __builtin_amdgcn_global_load_lds((const __attribute__((address_space(1))) uint32_t*)g,
                                     (__attribute__((address_space(3))) uint32_t*)l, 16, 0, 0);
}

// ---------------- f32 -> bf16 convert (vectorized) ----------------
__global__ void cvt_kernel(const float* __restrict__ in, u16* __restrict__ out, int n4) {
    int i = blockIdx.x * blockDim.x + threadIdx.x;
    int stride = gridDim.x * blockDim.x;
    for (; i < n4; i += stride) {
        float4 v = ((const float4*)in)[i];
        ushort4 o;
        o.x = f2bf(v.x); o.y = f2bf(v.y); o.z = f2bf(v.z); o.w = f2bf(v.w);
        ((ushort4*)out)[i] = o;
    }
}

// ---------------- f32 [R][C] -> bf16 [C][R] transpose-convert ----------------
__global__ void tcvt_kernel(const float* __restrict__ in, u16* __restrict__ out, int R, int C) {
    __shared__ float tile[32][33];
    int c0 = blockIdx.x * 32, r0 = blockIdx.y * 32;
    int tx = threadIdx.x, ty = threadIdx.y;  // 32 x 8
#pragma unroll
    for (int i = 0; i < 32; i += 8)
        tile[ty + i][tx] = in[(size_t)(r0 + ty + i) * C + c0 + tx];
    __syncthreads();
#pragma unroll
    for (int i = 0; i < 32; i += 8)
        out[(size_t)(c0 + ty + i) * R + r0 + tx] = f2bf(tile[tx][ty + i]);
}

// ---------------- llama3 RoPE cos/sin tables [T][64] ----------------
__global__ void rope_setup(float* __restrict__ cosT, float* __restrict__ sinT) {
    int t = blockIdx.x, d = threadIdx.x;  // 64 threads
    const float TWO_PI = 6.283185307179586f;
    float fidx = (float)d * (1.0f / 64.0f);
    float freq = (1.0f / TWO_PI) * powf(500000.0f, -fidx);
    const float factor = 32.0f, lo = 1.0f, hi = 4.0f, L0 = 8192.0f;
    float fl = lo / L0, fh = hi / L0;
    float smooth = fminf(fmaxf((L0 * freq - lo) / (hi - lo), 0.0f), 1.0f);
    float fs = (1.0f - smooth) * (freq / factor) + smooth * freq;
    float fr = (freq < fl) ? (freq / factor) : freq;
    if (freq >= fl && freq <= fh) fr = fs;
    float ang = TWO_PI * (float)t * fr;
    cosT[t * 64 + d] = cosf(ang);
    sinT[t * 64 + d] = sinf(ang);
}

// ---------------- in-place RoPE on bf16 [T][nheads*128] ----------------
__global__ void rope_apply(u16* __restrict__ x, const float* __restrict__ cosT,
                           const float* __restrict__ sinT, int nheads) {
    int i = blockIdx.x * blockDim.x + threadIdx.x;
    int total = T_SEQ * nheads * 64;
    if (i >= total) return;
    int d = i & 63;
    int h = (i >> 6) % nheads;
    int t = i / (nheads * 64);
    size_t base = (size_t)t * (nheads * 128) + h * 128 + d;
    float x0 = bf2f(x[base]), x1 = bf2f(x[base + 64]);
    float c = cosT[t * 64 + d], s = sinT[t * 64 + d];
    x[base] = f2bf(x0 * c - x1 * s);
    x[base + 64] = f2bf(x1 * c + x0 * s);
}

// ---------------- GEMM: C[M,N] = A[M,K] * Bt[N,K]^T (bf16 in, f32 acc) ----------------
// m97 structure: global_load_lds width-16 staging into LINEAR [128][64] LDS.
__launch_bounds__(256, 2)
__global__ void gemm_bt(const u16* __restrict__ A, const u16* __restrict__ Bt,
                        void* __restrict__ Cout, int M, int N, int K, int f32out) {
    __shared__ u16 As[128][64];
    __shared__ u16 Bs[128][64];
    int m0 = blockIdx.y * 128, n0 = blockIdx.x * 128;
    int tid = threadIdx.x;
    int wave = tid >> 6, lane = tid & 63;
    int l15 = lane & 15, lg = lane >> 4;
    int wm = (wave >> 1) * 64, wn = (wave & 1) * 64;
    f32x4 acc[4][4] = {};
    int rowb = tid >> 3, ch = (tid & 7) * 8;  // rowb 0..31, ch 0,8,..,56
    const u16* Ag = A + (size_t)(m0 + rowb) * K + ch;
    const u16* Bg = Bt + (size_t)(n0 + rowb) * K + ch;
    u16* Al = &As[rowb][ch];
    u16* Bl = &Bs[rowb][ch];

    for (int k0 = 0; k0 < K; k0 += 64) {
        __syncthreads();
#pragma unroll
        for (int p = 0; p < 4; ++p) {
            gload_lds16(Ag + (size_t)(p * 32) * K + k0, Al + p * 32 * 64);
            gload_lds16(Bg + (size_t)(p * 32) * K + k0, Bl + p * 32 * 64);
        }
        __syncthreads();
#pragma unroll
        for (int kk = 0; kk < 64; kk += 32) {
            bf16x8 af[4], bfr[4];
#pragma unroll
            for (int mi = 0; mi < 4; ++mi)
                af[mi] = *(const bf16x8*)&As[wm + mi * 16 + l15][kk + lg * 8];
#pragma unroll
            for (int ni = 0; ni < 4; ++ni)
                bfr[ni] = *(const bf16x8*)&Bs[wn + ni * 16 + l15][kk + lg * 8];
#pragma unroll
            for (int mi = 0; mi < 4; ++mi)
#pragma unroll
                for (int ni = 0; ni < 4; ++ni)
                    acc[mi][ni] = __builtin_amdgcn_mfma_f32_16x16x32_bf16(af[mi], bfr[ni], acc[mi][ni], 0, 0, 0);
        }
    }
#pragma unroll
    for (int mi = 0; mi < 4; ++mi)
#pragma unroll
        for (int ni = 0; ni < 4; ++ni)
#pragma unroll
            for (int r = 0; r < 4; ++r) {
                int row = m0 + wm + mi * 16 + lg * 4 + r;
                int col = n0 + wn + ni * 16 + l15;
                float v = acc[mi][ni][r];
                if (f32out)
                    ((float*)Cout)[(size_t)row * N + col] = v;
                else
                    ((u16*)Cout)[(size_t)row * N + col] = f2bf(v);
            }
}

// ---------------- flash attention (causal, GQA) ----------------
// grid: (T/64, NHEADS); block 256 = 4 waves x 16 q-rows.
// LPT: longest blocks (largest q0) dispatch first.
__launch_bounds__(256, 2)
__global__ void attn_kernel(const u16* __restrict__ Q, const u16* __restrict__ K,
                            const u16* __restrict__ V, u16* __restrict__ ctx) {
    __shared__ u16 Ks[64][136];
    __shared__ u16 Vs[128][72];   // transposed: [d][kv]
    __shared__ u16 Ps[4][16][72];
    int q0 = (gridDim.x - 1 - blockIdx.x) * 64;   // longest-first scheduling
    int h = blockIdx.y;
    int kvh = h >> 2;
    int tid = threadIdx.x;
    int wave = tid >> 6, lane = tid & 63;
    int l15 = lane & 15, lg = lane >> 4;
    int qrow_base = q0 + wave * 16;

    bf16x8 qf[4];
#pragma unroll
    for (int kk = 0; kk < 4; ++kk)
        qf[kk] = *(const bf16x8*)&Q[(size_t)(qrow_base + l15) * DMODEL + h * DHEAD + kk * 32 + lg * 8];

    f32x4 acc_o[8] = {};
    float m_run[4], l_run[4];
#pragma unroll
    for (int r = 0; r < 4; ++r) { m_run[r] = -1e30f; l_run[r] = 0.0f; }

    int rowb = tid >> 4, cb = tid & 15, chb = cb * 8;
    int ntiles = (q0 >> 6) + 1;
    for (int tkv = 0; tkv < ntiles; ++tkv) {
        int kv0 = tkv * 64;
        __syncthreads();
#pragma unroll
        for (int p = 0; p < 4; ++p) {
            int r = rowb + p * 16;
            uint4 kvv = *(const uint4*)&K[(size_t)(kv0 + r) * DKV + kvh * DHEAD + chb];
            *(uint4*)&Ks[r][chb] = kvv;
            uint4 vvv = *(const uint4*)&V[(size_t)(kv0 + r) * DKV + kvh * DHEAD + chb];
            u16* vsp = (u16*)&vvv;
#pragma unroll
            for (int ii = 0; ii < 8; ++ii) {
                int j = (ii + cb) & 7;  // stagger to avoid 16-way bank conflict
                Vs[chb + j][r] = vsp[j];
            }
        }
        __syncthreads();

        // S = Q K^T   (16 x 64 per wave)
        f32x4 sacc[4] = {};
#pragma unroll
        for (int nt = 0; nt < 4; ++nt)
#pragma unroll
            for (int kk = 0; kk < 4; ++kk) {
                bf16x8 kf = *(const bf16x8*)&Ks[nt * 16 + l15][kk * 32 + lg * 8];
                sacc[nt] = __builtin_amdgcn_mfma_f32_16x16x32_bf16(qf[kk], kf, sacc[nt], 0, 0, 0);
            }

        const float scale = 0.08838834764831845f;  // 1/sqrt(128)
#pragma unroll
        for (int r = 0; r < 4; ++r) {
            int qrow = qrow_base + lg * 4 + r;
            float mx = m_run[r];
            float sv[4];
#pragma unroll
            for (int nt = 0; nt < 4; ++nt) {
                int kcol = kv0 + nt * 16 + l15;
                float s = sacc[nt][r] * scale;
                if (kcol > qrow) s = -1e30f;
                sv[nt] = s;
                mx = fmaxf(mx, s);
            }
#pragma unroll
            for (int m = 1; m < 16; m <<= 1) mx = fmaxf(mx, __shfl_xor(mx, m, 64));
            float alpha = __expf(m_run[r] - mx);
            m_run[r] = mx;
            float psum = 0.0f;
#pragma unroll
            for (int nt = 0; nt < 4; ++nt) {
                float p = __expf(sv[nt] - mx);
                psum += p;
                Ps[wave][lg * 4 + r][nt * 16 + l15] = f2bf(p);
            }
#pragma unroll
            for (int m = 1; m < 16; m <<= 1) psum += __shfl_xor(psum, m, 64);
            l_run[r] = l_run[r] * alpha + psum;
#pragma unroll
            for (int dt = 0; dt < 8; ++dt) acc_o[dt][r] *= alpha;
        }

        // PV: O += P (16x64) * V (64x128)
        bf16x8 pf[2];
#pragma unroll
        for (int kt = 0; kt < 2; ++kt)
            pf[kt] = *(const bf16x8*)&Ps[wave][l15][kt * 32 + lg * 8];
#pragma unroll
        for (int dt = 0; dt < 8; ++dt)
#pragma unroll
            for (int kt = 0; kt < 2; ++kt) {
                bf16x8 vf = *(const bf16x8*)&Vs[dt * 16 + l15][kt * 32 + lg * 8];
                acc_o[dt] = __builtin_amdgcn_mfma_f32_16x16x32_bf16(pf[kt], vf, acc_o[dt], 0, 0, 0);
            }
        __syncthreads();
    }

#pragma unroll
    for (int dt = 0; dt < 8; ++dt)
#pragma unroll
        for (int r = 0; r < 4; ++r) {
            int row = qrow_base + lg * 4 + r;
            int col = h * DHEAD + dt * 16 + l15;
            ctx[(size_t)row * DMODEL + col] = f2bf(acc_o[dt][r] / l_run[r]);
        }
}

extern "C" void kernel_launch(void* const* d_in, const int* in_sizes, int n_in,
                              void* d_out, int out_size, void* d_ws, size_t ws_size,
                              hipStream_t stream) {
    const float* resid = (const float*)d_in[0];
    const float* Wq = (const float*)d_in[1];
    const float* Wk = (const float*)d_in[2];
    const float* Wv = (const float*)d_in[3];
    const float* Wo = (const float*)d_in[4];

    char* ws = (char*)d_ws;
    u16* Xb   = (u16*)(ws + 0);           // 2048x4096 bf16 = 16 MiB
    u16* WqT  = (u16*)(ws + 16777216);    // 4096x4096 bf16 = 32 MiB
    u16* WkT  = (u16*)(ws + 50331648);    // 1024x4096 bf16 = 8 MiB
    u16* WvT  = (u16*)(ws + 58720256);    // 8 MiB
    u16* WoT  = (u16*)(ws + 67108864);    // 32 MiB
    u16* Qf   = (u16*)(ws + 100663296);   // 2048x4096 bf16
    u16* Kf   = (u16*)(ws + 117440512);   // 2048x1024 bf16
    u16* Vf   = (u16*)(ws + 121634816);   // 2048x1024 bf16
    u16* ctx  = (u16*)(ws + 125829120);   // 2048x4096 bf16
    float* cosT = (float*)(ws + 142606336);
    float* sinT = (float*)(ws + 143130624);

    // converts + transposes
    cvt_kernel<<<2048, 256, 0, stream>>>(resid, Xb, T_SEQ * DMODEL / 4);
    dim3 tb(32, 8);
    tcvt_kernel<<<dim3(DMODEL / 32, DMODEL / 32), tb, 0, stream>>>(Wq, WqT, DMODEL, DMODEL);
    tcvt_kernel<<<dim3(DKV / 32, DMODEL / 32), tb, 0, stream>>>(Wk, WkT, DMODEL, DKV);
    tcvt_kernel<<<dim3(DKV / 32, DMODEL / 32), tb, 0, stream>>>(Wv, WvT, DMODEL, DKV);
    tcvt_kernel<<<dim3(DMODEL / 32, DMODEL / 32), tb, 0, stream>>>(Wo, WoT, DMODEL, DMODEL);
    rope_setup<<<T_SEQ, 64, 0, stream>>>(cosT, sinT);

    // projections
    gemm_bt<<<dim3(DMODEL / 128, T_SEQ / 128), 256, 0, stream>>>(Xb, WqT, Qf, T_SEQ, DMODEL, DMODEL, 0);
    gemm_bt<<<dim3(DKV / 128, T_SEQ / 128), 256, 0, stream>>>(Xb, WkT, Kf, T_SEQ, DKV, DMODEL, 0);
    gemm_bt<<<dim3(DKV / 128, T_SEQ / 128), 256, 0, stream>>>(Xb, WvT, Vf, T_SEQ, DKV, DMODEL, 0);

    // RoPE (in-place)
    rope_apply<<<(T_SEQ * NHEADS * 64 + 255) / 256, 256, 0, stream>>>(Qf, cosT, sinT, NHEADS);
    rope_apply<<<(T_SEQ * NKV * 64 + 255) / 256, 256, 0, stream>>>(Kf, cosT, sinT, NKV);

    // attention
    attn_kernel<<<dim3(T_SEQ / 64, NHEADS), 256, 0, stream>>>(Qf, Kf, Vf, ctx);

    // output projection (f32 out)
    gemm_bt<<<dim3(DMODEL / 128, T_SEQ / 128), 256, 0, stream>>>(ctx, WoT, d_out, T_SEQ, DMODEL, DMODEL, 1);
}

// Round 3
// 502.816 us; speedup vs baseline: 1.3993x; 1.3677x over previous
//
#include <hip/hip_runtime.h>
#include <stdint.h>

#define T_SEQ 2048
#define DMODEL 4096
#define DKV 1024
#define DHEAD 128
#define NHEADS 32
#define NKV 8

typedef unsigned short u16;
typedef __attribute__((ext_vector_type(8))) __bf16 bf16x8;
typedef __attribute__((ext_vector_type(4))) float f32x4;

__device__ __forceinline__ u16 f2bf(float f) {
    uint32_t u = __builtin_bit_cast(uint32_t, f);
    u += 0x7FFFu + ((u >> 16) & 1u);
    return (u16)(u >> 16);
}
__device__ __forceinline__ float bf2f(u16 b) {
    return __builtin_bit_cast(float, (uint32_t)b << 16);
}

__device__ __forceinline__ void gload_lds16(const u16* g, u16* l) {
    __builtin_amdgcn_global_load_lds((const __attribute__((address_space(1))) uint32_t*)g,
                                     (__attribute__((address_space(3))) uint32_t*)l, 16, 0, 0);
}

// ---------------- f32 -> bf16 convert (vectorized) ----------------
__global__ void cvt_kernel(const float* __restrict__ in, u16* __restrict__ out, int n4) {
    int i = blockIdx.x * blockDim.x + threadIdx.x;
    int stride = gridDim.x * blockDim.x;
    for (; i < n4; i += stride) {
        float4 v = ((const float4*)in)[i];
        ushort4 o;
        o.x = f2bf(v.x); o.y = f2bf(v.y); o.z = f2bf(v.z); o.w = f2bf(v.w);
        ((ushort4*)out)[i] = o;
    }
}

// ---------------- f32 [R][C] -> bf16 [C][R] transpose-convert ----------------
__global__ void tcvt_kernel(const float* __restrict__ in, u16* __restrict__ out, int R, int C) {
    __shared__ float tile[32][33];
    int c0 = blockIdx.x * 32, r0 = blockIdx.y * 32;
    int tx = threadIdx.x, ty = threadIdx.y;  // 32 x 8
#pragma unroll
    for (int i = 0; i < 32; i += 8)
        tile[ty + i][tx] = in[(size_t)(r0 + ty + i) * C + c0 + tx];
    __syncthreads();
#pragma unroll
    for (int i = 0; i < 32; i += 8)
        out[(size_t)(c0 + ty + i) * R + r0 + tx] = f2bf(tile[tx][ty + i]);
}

// ---------------- llama3 RoPE cos/sin tables [T][64] ----------------
__global__ void rope_setup(float* __restrict__ cosT, float* __restrict__ sinT) {
    int t = blockIdx.x, d = threadIdx.x;  // 64 threads
    const float TWO_PI = 6.283185307179586f;
    float fidx = (float)d * (1.0f / 64.0f);
    float freq = (1.0f / TWO_PI) * powf(500000.0f, -fidx);
    const float factor = 32.0f, lo = 1.0f, hi = 4.0f, L0 = 8192.0f;
    float fl = lo / L0, fh = hi / L0;
    float smooth = fminf(fmaxf((L0 * freq - lo) / (hi - lo), 0.0f), 1.0f);
    float fs = (1.0f - smooth) * (freq / factor) + smooth * freq;
    float fr = (freq < fl) ? (freq / factor) : freq;
    if (freq >= fl && freq <= fh) fr = fs;
    float ang = TWO_PI * (float)t * fr;
    cosT[t * 64 + d] = cosf(ang);
    sinT[t * 64 + d] = sinf(ang);
}

// ---------------- in-place RoPE on bf16 [T][nheads*128] ----------------
__global__ void rope_apply(u16* __restrict__ x, const float* __restrict__ cosT,
                           const float* __restrict__ sinT, int nheads) {
    int i = blockIdx.x * blockDim.x + threadIdx.x;
    int total = T_SEQ * nheads * 64;
    if (i >= total) return;
    int d = i & 63;
    int h = (i >> 6) % nheads;
    int t = i / (nheads * 64);
    size_t base = (size_t)t * (nheads * 128) + h * 128 + d;
    float x0 = bf2f(x[base]), x1 = bf2f(x[base + 64]);
    float c = cosT[t * 64 + d], s = sinT[t * 64 + d];
    x[base] = f2bf(x0 * c - x1 * s);
    x[base + 64] = f2bf(x1 * c + x0 * s);
}

// ---------------- GEMM: C[M,N] = A[M,K] * Bt[N,K]^T (bf16 in, f32 acc) ----------------
__launch_bounds__(256, 2)
__global__ void gemm_bt(const u16* __restrict__ A, const u16* __restrict__ Bt,
                        void* __restrict__ Cout, int M, int N, int K, int f32out) {
    __shared__ u16 As[128][64];
    __shared__ u16 Bs[128][64];
    int m0 = blockIdx.y * 128, n0 = blockIdx.x * 128;
    int tid = threadIdx.x;
    int wave = tid >> 6, lane = tid & 63;
    int l15 = lane & 15, lg = lane >> 4;
    int wm = (wave >> 1) * 64, wn = (wave & 1) * 64;
    f32x4 acc[4][4] = {};
    int rowb = tid >> 3, ch = (tid & 7) * 8;  // rowb 0..31, ch 0,8,..,56
    const u16* Ag = A + (size_t)(m0 + rowb) * K + ch;
    const u16* Bg = Bt + (size_t)(n0 + rowb) * K + ch;
    u16* Al = &As[rowb][ch];
    u16* Bl = &Bs[rowb][ch];

    for (int k0 = 0; k0 < K; k0 += 64) {
        __syncthreads();
#pragma unroll
        for (int p = 0; p < 4; ++p) {
            gload_lds16(Ag + (size_t)(p * 32) * K + k0, Al + p * 32 * 64);
            gload_lds16(Bg + (size_t)(p * 32) * K + k0, Bl + p * 32 * 64);
        }
        __syncthreads();
#pragma unroll
        for (int kk = 0; kk < 64; kk += 32) {
            bf16x8 af[4], bfr[4];
#pragma unroll
            for (int mi = 0; mi < 4; ++mi)
                af[mi] = *(const bf16x8*)&As[wm + mi * 16 + l15][kk + lg * 8];
#pragma unroll
            for (int ni = 0; ni < 4; ++ni)
                bfr[ni] = *(const bf16x8*)&Bs[wn + ni * 16 + l15][kk + lg * 8];
#pragma unroll
            for (int mi = 0; mi < 4; ++mi)
#pragma unroll
                for (int ni = 0; ni < 4; ++ni)
                    acc[mi][ni] = __builtin_amdgcn_mfma_f32_16x16x32_bf16(af[mi], bfr[ni], acc[mi][ni], 0, 0, 0);
        }
    }
#pragma unroll
    for (int mi = 0; mi < 4; ++mi)
#pragma unroll
        for (int ni = 0; ni < 4; ++ni)
#pragma unroll
            for (int r = 0; r < 4; ++r) {
                int row = m0 + wm + mi * 16 + lg * 4 + r;
                int col = n0 + wn + ni * 16 + l15;
                float v = acc[mi][ni][r];
                if (f32out)
                    ((float*)Cout)[(size_t)row * N + col] = v;
                else
                    ((u16*)Cout)[(size_t)row * N + col] = f2bf(v);
            }
}

// ---------------- flash attention (causal, GQA) ----------------
// grid: (NHEADS, T/64); block 256 = 4 waves x 16 q-rows.
// Double-buffered K/V via global_load_lds with source-side XOR swizzle;
// row-sum via ones-column MFMA; defer-max rescale; LPT (long q-tiles first).
__launch_bounds__(256, 2)
__global__ void attn_kernel(const u16* __restrict__ Q, const u16* __restrict__ K,
                            const u16* __restrict__ Vt, u16* __restrict__ ctx) {
    __shared__ u16 Ks[2][64][128];   // [kv][d], chunk c of row r stored at slot c^(r&15)
    __shared__ u16 Vs[2][128][64];   // [d][kv], chunk c of row r stored at slot c^(r&7)
    __shared__ u16 Ones[16][64];     // row 0 = 1.0, rows 1..15 = 0
    __shared__ u16 Ps[4][16][72];
    int h = blockIdx.x;
    int q0 = ((int)gridDim.y - 1 - (int)blockIdx.y) * 64;  // longest-first
    int kvh = h >> 2;
    int tid = threadIdx.x;
    int lane = tid & 63;
    int wave = tid >> 6;
    int l15 = lane & 15, lg = lane >> 4;
    int qrow_base = q0 + wave * 16;

    // init ones tile (before first barrier)
    {
        int idx = tid * 4;
        u16 val = (idx < 64) ? (u16)0x3F80 : (u16)0;
        u16* p = &Ones[0][0] + idx;
        p[0] = val; p[1] = val; p[2] = val; p[3] = val;
    }

    bf16x8 qf[4];
#pragma unroll
    for (int kk = 0; kk < 4; ++kk)
        qf[kk] = *(const bf16x8*)&Q[(size_t)(qrow_base + l15) * DMODEL + h * DHEAD + kk * 32 + lg * 8];

    // staging geometry (source-side swizzle, LDS linear by lane)
    int krow = tid >> 4, kj = tid & 15;   // K: 16 rows/call, 16 chunks/row
    int vrow = tid >> 3, vj = tid & 7;    // V: 32 rows/call, 8 chunks/row
    const u16* Kg = K + (size_t)krow * DKV + kvh * DHEAD + ((kj ^ krow) * 8);
    const u16* Vg = Vt + (size_t)(kvh * DHEAD + vrow) * T_SEQ + ((vj ^ (vrow & 7)) * 8);
    u16* Kl = &Ks[0][0][0] + tid * 8;
    u16* Vl = &Vs[0][0][0] + tid * 8;
    const int BUFK = 64 * 128;  // u16 per K buffer
    const int BUFV = 128 * 64;

#define STAGE(buf, kv0)                                                              \
    {                                                                                \
        _Pragma("unroll")                                                            \
        for (int p = 0; p < 4; ++p) {                                                \
            gload_lds16(Kg + (size_t)((kv0) + p * 16) * DKV, Kl + (buf) * BUFK + p * 2048); \
            gload_lds16(Vg + (kv0) + (size_t)(p * 32) * T_SEQ, Vl + (buf) * BUFV + p * 2048); \
        }                                                                            \
    }

    f32x4 acc_o[8] = {};
    f32x4 acc_l = {0.f, 0.f, 0.f, 0.f};
    float m_run[4];
#pragma unroll
    for (int r = 0; r < 4; ++r) m_run[r] = -1e30f;

    int ntiles = (q0 >> 6) + 1;
    STAGE(0, 0);

    for (int t = 0; t < ntiles; ++t) {
        int cur = t & 1;
        __syncthreads();                       // staged buf[cur] visible; prior reads of buf[cur^1] done
        if (t + 1 < ntiles) STAGE(cur ^ 1, (t + 1) * 64);

        const u16* ksb = &Ks[cur][0][0];
        const u16* vsb = &Vs[cur][0][0];
        int kv0 = t * 64;

        // S = Q K^T  (16 x 64 per wave)
        f32x4 sacc[4] = {};
#pragma unroll
        for (int nt = 0; nt < 4; ++nt)
#pragma unroll
            for (int kk = 0; kk < 4; ++kk) {
                int row = nt * 16 + l15;
                int slot = (kk * 4 + lg) ^ l15;
                bf16x8 kf = *(const bf16x8*)(ksb + row * 128 + slot * 8);
                sacc[nt] = __builtin_amdgcn_mfma_f32_16x16x32_bf16(qf[kk], kf, sacc[nt], 0, 0, 0);
            }

        const float scale = 0.08838834764831845f;  // 1/sqrt(128)
        bool diag = (t == ntiles - 1);
#pragma unroll
        for (int r = 0; r < 4; ++r) {
            int qrow = qrow_base + lg * 4 + r;
            float sv[4];
            float pmax = -1e30f;
#pragma unroll
            for (int nt = 0; nt < 4; ++nt) {
                float s = sacc[nt][r] * scale;
                if (diag && (kv0 + nt * 16 + l15 > qrow)) s = -1e30f;
                sv[nt] = s;
                pmax = fmaxf(pmax, s);
            }
#pragma unroll
            for (int m = 1; m < 16; m <<= 1) pmax = fmaxf(pmax, __shfl_xor(pmax, m, 64));
            if (__any(pmax > m_run[r] + 8.0f)) {           // defer-max (T13)
                float mnew = fmaxf(m_run[r], pmax);
                float alpha = __expf(m_run[r] - mnew);
                m_run[r] = mnew;
#pragma unroll
                for (int dt = 0; dt < 8; ++dt) acc_o[dt][r] *= alpha;
                acc_l[r] *= alpha;
            }
#pragma unroll
            for (int nt = 0; nt < 4; ++nt)
                Ps[wave][lg * 4 + r][nt * 16 + l15] = f2bf(__expf(sv[nt] - m_run[r]));
        }

        // PV: O += P (16x64) * V (64x128);  l += P * ones
        bf16x8 pf[2];
#pragma unroll
        for (int kt = 0; kt < 2; ++kt)
            pf[kt] = *(const bf16x8*)&Ps[wave][l15][kt * 32 + lg * 8];
#pragma unroll
        for (int kt = 0; kt < 2; ++kt) {
            int oslot = (kt * 4 + lg) ^ (l15 & 7);
            bf16x8 of = *(const bf16x8*)(&Ones[0][0] + l15 * 64 + oslot * 8);
            acc_l = __builtin_amdgcn_mfma_f32_16x16x32_bf16(pf[kt], of, acc_l, 0, 0, 0);
        }
#pragma unroll
        for (int dt = 0; dt < 8; ++dt)
#pragma unroll
            for (int kt = 0; kt < 2; ++kt) {
                int vr = dt * 16 + l15;
                int slot = (kt * 4 + lg) ^ (l15 & 7);
                bf16x8 vf = *(const bf16x8*)(vsb + vr * 64 + slot * 8);
                acc_o[dt] = __builtin_amdgcn_mfma_f32_16x16x32_bf16(pf[kt], vf, acc_o[dt], 0, 0, 0);
            }
    }
#undef STAGE

#pragma unroll
    for (int r = 0; r < 4; ++r) {
        float lsum = __shfl(acc_l[r], lg * 16, 64);  // col 0 of the sum tile
        float inv = 1.0f / lsum;
#pragma unroll
        for (int dt = 0; dt < 8; ++dt) {
            int row = qrow_base + lg * 4 + r;
            int col = h * DHEAD + dt * 16 + l15;
            ctx[(size_t)row * DMODEL + col] = f2bf(acc_o[dt][r] * inv);
        }
    }
}

extern "C" void kernel_launch(void* const* d_in, const int* in_sizes, int n_in,
                              void* d_out, int out_size, void* d_ws, size_t ws_size,
                              hipStream_t stream) {
    const float* resid = (const float*)d_in[0];
    const float* Wq = (const float*)d_in[1];
    const float* Wk = (const float*)d_in[2];
    const float* Wv = (const float*)d_in[3];
    const float* Wo = (const float*)d_in[4];

    char* ws = (char*)d_ws;
    u16* Xb   = (u16*)(ws + 0);           // 2048x4096 bf16 = 16 MiB
    u16* WqT  = (u16*)(ws + 16777216);    // 4096x4096 bf16 = 32 MiB
    u16* WkT  = (u16*)(ws + 50331648);    // 1024x4096 bf16 = 8 MiB
    u16* WvT  = (u16*)(ws + 58720256);    // 8 MiB
    u16* WoT  = (u16*)(ws + 67108864);    // 32 MiB
    u16* Qf   = (u16*)(ws + 100663296);   // 2048x4096 bf16
    u16* Kf   = (u16*)(ws + 117440512);   // 2048x1024 bf16
    u16* Vt   = (u16*)(ws + 121634816);   // 1024x2048 bf16 (V transposed: [d][t])
    u16* ctx  = (u16*)(ws + 125829120);   // 2048x4096 bf16
    float* cosT = (float*)(ws + 142606336);
    float* sinT = (float*)(ws + 143130624);

    // converts + transposes
    cvt_kernel<<<2048, 256, 0, stream>>>(resid, Xb, T_SEQ * DMODEL / 4);
    dim3 tb(32, 8);
    tcvt_kernel<<<dim3(DMODEL / 32, DMODEL / 32), tb, 0, stream>>>(Wq, WqT, DMODEL, DMODEL);
    tcvt_kernel<<<dim3(DKV / 32, DMODEL / 32), tb, 0, stream>>>(Wk, WkT, DMODEL, DKV);
    tcvt_kernel<<<dim3(DKV / 32, DMODEL / 32), tb, 0, stream>>>(Wv, WvT, DMODEL, DKV);
    tcvt_kernel<<<dim3(DMODEL / 32, DMODEL / 32), tb, 0, stream>>>(Wo, WoT, DMODEL, DMODEL);
    rope_setup<<<T_SEQ, 64, 0, stream>>>(cosT, sinT);

    // projections
    gemm_bt<<<dim3(DMODEL / 128, T_SEQ / 128), 256, 0, stream>>>(Xb, WqT, Qf, T_SEQ, DMODEL, DMODEL, 0);
    gemm_bt<<<dim3(DKV / 128, T_SEQ / 128), 256, 0, stream>>>(Xb, WkT, Kf, T_SEQ, DKV, DMODEL, 0);
    // V projection computed TRANSPOSED: Vt[d][t] = (Xb . WvT^T)^T  (operands swapped)
    gemm_bt<<<dim3(T_SEQ / 128, DKV / 128), 256, 0, stream>>>(WvT, Xb, Vt, DKV, T_SEQ, DMODEL, 0);

    // RoPE (in-place, Q and K only)
    rope_apply<<<(T_SEQ * NHEADS * 64 + 255) / 256, 256, 0, stream>>>(Qf, cosT, sinT, NHEADS);
    rope_apply<<<(T_SEQ * NKV * 64 + 255) / 256, 256, 0, stream>>>(Kf, cosT, sinT, NKV);

    // attention
    attn_kernel<<<dim3(NHEADS, T_SEQ / 64), 256, 0, stream>>>(Qf, Kf, Vt, ctx);

    // output projection (f32 out)
    gemm_bt<<<dim3(DMODEL / 128, T_SEQ / 128), 256, 0, stream>>>(ctx, WoT, d_out, T_SEQ, DMODEL, DMODEL, 1);
}

// Round 4
// 377.459 us; speedup vs baseline: 1.8640x; 1.3321x over previous
//
#include <hip/hip_runtime.h>
#include <stdint.h>

#define T_SEQ 2048
#define DMODEL 4096
#define DQKV 6144          // fused Q(4096) + K(1024) + V(1024) output width
#define KOFF 4096          // K column offset in QKV
#define VOFF 5120          // V column offset in QKV
#define DHEAD 128
#define NHEADS 32
#define NKV 8

typedef unsigned short u16;
typedef __attribute__((ext_vector_type(8))) __bf16 bf16x8;
typedef __attribute__((ext_vector_type(4))) float f32x4;

__device__ __forceinline__ u16 f2bf(float f) {
    uint32_t u = __builtin_bit_cast(uint32_t, f);
    u += 0x7FFFu + ((u >> 16) & 1u);
    return (u16)(u >> 16);
}
__device__ __forceinline__ float bf2f(u16 b) {
    return __builtin_bit_cast(float, (uint32_t)b << 16);
}

__device__ __forceinline__ void gload_lds16(const u16* g, u16* l) {
    __builtin_amdgcn_global_load_lds((const __attribute__((address_space(1))) uint32_t*)g,
                                     (__attribute__((address_space(3))) uint32_t*)l, 16, 0, 0);
}

// ---------------- f32 -> bf16 convert (vectorized) ----------------
__global__ void cvt_kernel(const float* __restrict__ in, u16* __restrict__ out, int n4) {
    int i = blockIdx.x * blockDim.x + threadIdx.x;
    int stride = gridDim.x * blockDim.x;
    for (; i < n4; i += stride) {
        float4 v = ((const float4*)in)[i];
        ushort4 o;
        o.x = f2bf(v.x); o.y = f2bf(v.y); o.z = f2bf(v.z); o.w = f2bf(v.w);
        ((ushort4*)out)[i] = o;
    }
}

// ---------------- f32 [R][C] -> bf16 [C][R] transpose-convert ----------------
__global__ void tcvt_kernel(const float* __restrict__ in, u16* __restrict__ out, int R, int C) {
    __shared__ float tile[32][33];
    int c0 = blockIdx.x * 32, r0 = blockIdx.y * 32;
    int tx = threadIdx.x, ty = threadIdx.y;  // 32 x 8
#pragma unroll
    for (int i = 0; i < 32; i += 8)
        tile[ty + i][tx] = in[(size_t)(r0 + ty + i) * C + c0 + tx];
    __syncthreads();
#pragma unroll
    for (int i = 0; i < 32; i += 8)
        out[(size_t)(c0 + ty + i) * R + r0 + tx] = f2bf(tile[tx][ty + i]);
}

// ---------------- bf16 V-slice [T][.] -> Vt [D][T] transpose ----------------
__global__ void vtrans_kernel(const u16* __restrict__ QKV, u16* __restrict__ Vt) {
    __shared__ u16 tile[32][33];
    int t0 = blockIdx.x * 32, d0 = blockIdx.y * 32;
    int tx = threadIdx.x, ty = threadIdx.y;  // 32 x 8
#pragma unroll
    for (int i = 0; i < 32; i += 8)
        tile[ty + i][tx] = QKV[(size_t)(t0 + ty + i) * DQKV + VOFF + d0 + tx];
    __syncthreads();
#pragma unroll
    for (int i = 0; i < 32; i += 8)
        Vt[(size_t)(d0 + ty + i) * T_SEQ + t0 + tx] = tile[tx][ty + i];
}

// ---------------- llama3 RoPE cos/sin tables [T][64] ----------------
__global__ void rope_setup(float* __restrict__ cosT, float* __restrict__ sinT) {
    int t = blockIdx.x, d = threadIdx.x;  // 64 threads
    const float TWO_PI = 6.283185307179586f;
    float fidx = (float)d * (1.0f / 64.0f);
    float freq = (1.0f / TWO_PI) * powf(500000.0f, -fidx);
    const float factor = 32.0f, lo = 1.0f, hi = 4.0f, L0 = 8192.0f;
    float fl = lo / L0, fh = hi / L0;
    float smooth = fminf(fmaxf((L0 * freq - lo) / (hi - lo), 0.0f), 1.0f);
    float fs = (1.0f - smooth) * (freq / factor) + smooth * freq;
    float fr = (freq < fl) ? (freq / factor) : freq;
    if (freq >= fl && freq <= fh) fr = fs;
    float ang = TWO_PI * (float)t * fr;
    cosT[t * 64 + d] = cosf(ang);
    sinT[t * 64 + d] = sinf(ang);
}

// ---------------- in-place RoPE on bf16, arbitrary row stride / col offset ----------------
__global__ void rope_apply(u16* __restrict__ x, const float* __restrict__ cosT,
                           const float* __restrict__ sinT, int nheads, int rowstride, int coloff) {
    int i = blockIdx.x * blockDim.x + threadIdx.x;
    int total = T_SEQ * nheads * 64;
    if (i >= total) return;
    int d = i & 63;
    int h = (i >> 6) % nheads;
    int t = i / (nheads * 64);
    size_t base = (size_t)t * rowstride + coloff + h * 128 + d;
    float x0 = bf2f(x[base]), x1 = bf2f(x[base + 64]);
    float c = cosT[t * 64 + d], s = sinT[t * 64 + d];
    x[base] = f2bf(x0 * c - x1 * s);
    x[base + 64] = f2bf(x1 * c + x0 * s);
}

// ---------------- GEMM: C[M,N] = A[M,K] * Bt[N,K]^T (bf16 in, f32 acc) ----------------
// m97 structure: global_load_lds width-16 staging into LINEAR [128][64] LDS.
__launch_bounds__(256, 2)
__global__ void gemm_bt(const u16* __restrict__ A, const u16* __restrict__ Bt,
                        void* __restrict__ Cout, int M, int N, int K, int f32out) {
    __shared__ u16 As[128][64];
    __shared__ u16 Bs[128][64];
    int m0 = blockIdx.y * 128, n0 = blockIdx.x * 128;
    int tid = threadIdx.x;
    int wave = tid >> 6, lane = tid & 63;
    int l15 = lane & 15, lg = lane >> 4;
    int wm = (wave >> 1) * 64, wn = (wave & 1) * 64;
    f32x4 acc[4][4] = {};
    int rowb = tid >> 3, ch = (tid & 7) * 8;  // rowb 0..31, ch 0,8,..,56
    const u16* Ag = A + (size_t)(m0 + rowb) * K + ch;
    const u16* Bg = Bt + (size_t)(n0 + rowb) * K + ch;
    u16* Al = &As[rowb][ch];
    u16* Bl = &Bs[rowb][ch];

    for (int k0 = 0; k0 < K; k0 += 64) {
        __syncthreads();
#pragma unroll
        for (int p = 0; p < 4; ++p) {
            gload_lds16(Ag + (size_t)(p * 32) * K + k0, Al + p * 32 * 64);
            gload_lds16(Bg + (size_t)(p * 32) * K + k0, Bl + p * 32 * 64);
        }
        __syncthreads();
#pragma unroll
        for (int kk = 0; kk < 64; kk += 32) {
            bf16x8 af[4], bfr[4];
#pragma unroll
            for (int mi = 0; mi < 4; ++mi)
                af[mi] = *(const bf16x8*)&As[wm + mi * 16 + l15][kk + lg * 8];
#pragma unroll
            for (int ni = 0; ni < 4; ++ni)
                bfr[ni] = *(const bf16x8*)&Bs[wn + ni * 16 + l15][kk + lg * 8];
#pragma unroll
            for (int mi = 0; mi < 4; ++mi)
#pragma unroll
                for (int ni = 0; ni < 4; ++ni)
                    acc[mi][ni] = __builtin_amdgcn_mfma_f32_16x16x32_bf16(af[mi], bfr[ni], acc[mi][ni], 0, 0, 0);
        }
    }
#pragma unroll
    for (int mi = 0; mi < 4; ++mi)
#pragma unroll
        for (int ni = 0; ni < 4; ++ni)
#pragma unroll
            for (int r = 0; r < 4; ++r) {
                int row = m0 + wm + mi * 16 + lg * 4 + r;
                int col = n0 + wn + ni * 16 + l15;
                float v = acc[mi][ni][r];
                if (f32out)
                    ((float*)Cout)[(size_t)row * N + col] = v;
                else
                    ((u16*)Cout)[(size_t)row * N + col] = f2bf(v);
            }
}

// ---------------- flash attention (causal, GQA) ----------------
// grid: (NHEADS, T/64); block 256 = 4 waves x 16 q-rows.
// Q,K read from fused QKV buffer (row stride DQKV, K at col offset KOFF).
// Double-buffered K/V via global_load_lds with source-side XOR swizzle;
// row-sum via ones-column MFMA; defer-max rescale; LPT (long q-tiles first).
__launch_bounds__(256, 2)
__global__ void attn_kernel(const u16* __restrict__ QKV, const u16* __restrict__ Vt,
                            u16* __restrict__ ctx) {
    __shared__ u16 Ks[2][64][128];   // [kv][d], chunk c of row r stored at slot c^(r&15)
    __shared__ u16 Vs[2][128][64];   // [d][kv], chunk c of row r stored at slot c^(r&7)
    __shared__ u16 Ones[16][64];     // row 0 = 1.0, rows 1..15 = 0
    __shared__ u16 Ps[4][16][72];
    int h = blockIdx.x;
    int q0 = ((int)gridDim.y - 1 - (int)blockIdx.y) * 64;  // longest-first
    int kvh = h >> 2;
    int tid = threadIdx.x;
    int lane = tid & 63;
    int wave = tid >> 6;
    int l15 = lane & 15, lg = lane >> 4;
    int qrow_base = q0 + wave * 16;

    // init ones tile (before first barrier)
    {
        int idx = tid * 4;
        u16 val = (idx < 64) ? (u16)0x3F80 : (u16)0;
        u16* p = &Ones[0][0] + idx;
        p[0] = val; p[1] = val; p[2] = val; p[3] = val;
    }

    bf16x8 qf[4];
#pragma unroll
    for (int kk = 0; kk < 4; ++kk)
        qf[kk] = *(const bf16x8*)&QKV[(size_t)(qrow_base + l15) * DQKV + h * DHEAD + kk * 32 + lg * 8];

    // staging geometry (source-side swizzle, LDS linear by lane)
    int krow = tid >> 4, kj = tid & 15;   // K: 16 rows/call, 16 chunks/row
    int vrow = tid >> 3, vj = tid & 7;    // V: 32 rows/call, 8 chunks/row
    const u16* Kg = QKV + (size_t)krow * DQKV + KOFF + kvh * DHEAD + ((kj ^ krow) * 8);
    const u16* Vg = Vt + (size_t)(kvh * DHEAD + vrow) * T_SEQ + ((vj ^ (vrow & 7)) * 8);
    u16* Kl = &Ks[0][0][0] + tid * 8;
    u16* Vl = &Vs[0][0][0] + tid * 8;
    const int BUFK = 64 * 128;  // u16 per K buffer
    const int BUFV = 128 * 64;

#define STAGE(buf, kv0)                                                              \
    {                                                                                \
        _Pragma("unroll")                                                            \
        for (int p = 0; p < 4; ++p) {                                                \
            gload_lds16(Kg + (size_t)((kv0) + p * 16) * DQKV, Kl + (buf) * BUFK + p * 2048); \
            gload_lds16(Vg + (kv0) + (size_t)(p * 32) * T_SEQ, Vl + (buf) * BUFV + p * 2048); \
        }                                                                            \
    }

    f32x4 acc_o[8] = {};
    f32x4 acc_l = {0.f, 0.f, 0.f, 0.f};
    float m_run[4];
#pragma unroll
    for (int r = 0; r < 4; ++r) m_run[r] = -1e30f;

    int ntiles = (q0 >> 6) + 1;
    STAGE(0, 0);

    for (int t = 0; t < ntiles; ++t) {
        int cur = t & 1;
        __syncthreads();                       // staged buf[cur] visible; prior reads of buf[cur^1] done
        if (t + 1 < ntiles) STAGE(cur ^ 1, (t + 1) * 64);

        const u16* ksb = &Ks[cur][0][0];
        const u16* vsb = &Vs[cur][0][0];
        int kv0 = t * 64;

        // S = Q K^T  (16 x 64 per wave)
        f32x4 sacc[4] = {};
#pragma unroll
        for (int nt = 0; nt < 4; ++nt)
#pragma unroll
            for (int kk = 0; kk < 4; ++kk) {
                int row = nt * 16 + l15;
                int slot = (kk * 4 + lg) ^ l15;
                bf16x8 kf = *(const bf16x8*)(ksb + row * 128 + slot * 8);
                sacc[nt] = __builtin_amdgcn_mfma_f32_16x16x32_bf16(qf[kk], kf, sacc[nt], 0, 0, 0);
            }

        const float scale = 0.08838834764831845f;  // 1/sqrt(128)
        bool diag = (t == ntiles - 1);
#pragma unroll
        for (int r = 0; r < 4; ++r) {
            int qrow = qrow_base + lg * 4 + r;
            float sv[4];
            float pmax = -1e30f;
#pragma unroll
            for (int nt = 0; nt < 4; ++nt) {
                float s = sacc[nt][r] * scale;
                if (diag && (kv0 + nt * 16 + l15 > qrow)) s = -1e30f;
                sv[nt] = s;
                pmax = fmaxf(pmax, s);
            }
#pragma unroll
            for (int m = 1; m < 16; m <<= 1) pmax = fmaxf(pmax, __shfl_xor(pmax, m, 64));
            if (__any(pmax > m_run[r] + 8.0f)) {           // defer-max (T13)
                float mnew = fmaxf(m_run[r], pmax);
                float alpha = __expf(m_run[r] - mnew);
                m_run[r] = mnew;
#pragma unroll
                for (int dt = 0; dt < 8; ++dt) acc_o[dt][r] *= alpha;
                acc_l[r] *= alpha;
            }
#pragma unroll
            for (int nt = 0; nt < 4; ++nt)
                Ps[wave][lg * 4 + r][nt * 16 + l15] = f2bf(__expf(sv[nt] - m_run[r]));
        }

        // PV: O += P (16x64) * V (64x128);  l += P * ones
        bf16x8 pf[2];
#pragma unroll
        for (int kt = 0; kt < 2; ++kt)
            pf[kt] = *(const bf16x8*)&Ps[wave][l15][kt * 32 + lg * 8];
#pragma unroll
        for (int kt = 0; kt < 2; ++kt) {
            int oslot = (kt * 4 + lg) ^ (l15 & 7);
            bf16x8 of = *(const bf16x8*)(&Ones[0][0] + l15 * 64 + oslot * 8);
            acc_l = __builtin_amdgcn_mfma_f32_16x16x32_bf16(pf[kt], of, acc_l, 0, 0, 0);
        }
#pragma unroll
        for (int dt = 0; dt < 8; ++dt)
#pragma unroll
            for (int kt = 0; kt < 2; ++kt) {
                int vr = dt * 16 + l15;
                int slot = (kt * 4 + lg) ^ (l15 & 7);
                bf16x8 vf = *(const bf16x8*)(vsb + vr * 64 + slot * 8);
                acc_o[dt] = __builtin_amdgcn_mfma_f32_16x16x32_bf16(pf[kt], vf, acc_o[dt], 0, 0, 0);
            }
    }
#undef STAGE

#pragma unroll
    for (int r = 0; r < 4; ++r) {
        float lsum = __shfl(acc_l[r], lg * 16, 64);  // col 0 of the sum tile
        float inv = 1.0f / lsum;
#pragma unroll
        for (int dt = 0; dt < 8; ++dt) {
            int row = qrow_base + lg * 4 + r;
            int col = h * DHEAD + dt * 16 + l15;
            ctx[(size_t)row * DMODEL + col] = f2bf(acc_o[dt][r] * inv);
        }
    }
}

extern "C" void kernel_launch(void* const* d_in, const int* in_sizes, int n_in,
                              void* d_out, int out_size, void* d_ws, size_t ws_size,
                              hipStream_t stream) {
    const float* resid = (const float*)d_in[0];
    const float* Wq = (const float*)d_in[1];
    const float* Wk = (const float*)d_in[2];
    const float* Wv = (const float*)d_in[3];
    const float* Wo = (const float*)d_in[4];

    char* ws = (char*)d_ws;
    // ctx aliases Xb: Xb is dead after the fused QKV GEMM; attn writes ctx later (same stream).
    u16* Xb   = (u16*)(ws + 0);           // 2048x4096 bf16 = 16 MiB
    u16* ctx  = (u16*)(ws + 0);           // 2048x4096 bf16 (aliases Xb)
    u16* WqT  = (u16*)(ws + 16777216);    // rows    0..4095 of fused B^T (32 MiB)
    u16* WkT  = (u16*)(ws + 50331648);    // rows 4096..5119 (8 MiB)
    u16* WvT  = (u16*)(ws + 58720256);    // rows 5120..6143 (8 MiB)
    u16* WoT  = (u16*)(ws + 67108864);    // 32 MiB
    u16* QKV  = (u16*)(ws + 100663296);   // 2048x6144 bf16 = 24 MiB
    u16* Vt   = (u16*)(ws + 125829120);   // 1024x2048 bf16 = 4 MiB
    float* cosT = (float*)(ws + 130023424);
    float* sinT = (float*)(ws + 130547712);

    // converts + transposes
    cvt_kernel<<<2048, 256, 0, stream>>>(resid, Xb, T_SEQ * DMODEL / 4);
    dim3 tb(32, 8);
    tcvt_kernel<<<dim3(DMODEL / 32, DMODEL / 32), tb, 0, stream>>>(Wq, WqT, DMODEL, DMODEL);
    tcvt_kernel<<<dim3(1024 / 32, DMODEL / 32), tb, 0, stream>>>(Wk, WkT, DMODEL, 1024);
    tcvt_kernel<<<dim3(1024 / 32, DMODEL / 32), tb, 0, stream>>>(Wv, WvT, DMODEL, 1024);
    tcvt_kernel<<<dim3(DMODEL / 32, DMODEL / 32), tb, 0, stream>>>(Wo, WoT, DMODEL, DMODEL);
    rope_setup<<<T_SEQ, 64, 0, stream>>>(cosT, sinT);

    // fused QKV projection: [2048,6144] = Xb[2048,4096] x concat(WqT,WkT,WvT)^T
    gemm_bt<<<dim3(DQKV / 128, T_SEQ / 128), 256, 0, stream>>>(Xb, WqT, QKV, T_SEQ, DQKV, DMODEL, 0);

    // RoPE (in-place on fused buffer: Q cols 0..4095, K cols 4096..5119)
    rope_apply<<<(T_SEQ * NHEADS * 64 + 255) / 256, 256, 0, stream>>>(QKV, cosT, sinT, NHEADS, DQKV, 0);
    rope_apply<<<(T_SEQ * NKV * 64 + 255) / 256, 256, 0, stream>>>(QKV, cosT, sinT, NKV, DQKV, KOFF);

    // V transpose: Vt[d][t] = QKV[t][VOFF+d]
    vtrans_kernel<<<dim3(T_SEQ / 32, 1024 / 32), tb, 0, stream>>>(QKV, Vt);

    // attention
    attn_kernel<<<dim3(NHEADS, T_SEQ / 64), 256, 0, stream>>>(QKV, Vt, ctx);

    // output projection (f32 out)
    gemm_bt<<<dim3(DMODEL / 128, T_SEQ / 128), 256, 0, stream>>>(ctx, WoT, d_out, T_SEQ, DMODEL, DMODEL, 1);
}